// Round 1
// baseline (209.181 us; speedup 1.0000x reference)
//
#include <hip/hip_runtime.h>
#include <hip/hip_cooperative_groups.h>

namespace cg = cooperative_groups;

// out[1024][1024] = relu(a @ feats^T) @ relu(b @ feats^T)^T
//   a,b: [1024][2048] fp32, feats: [128][2048] fp32, out fp32.
// Single cooperative kernel, 512 blocks x 256 threads:
//   phase A: [a;b] @ feats^T split-K(16) -> fp32 partials in d_ws
//   grid.sync()
//   phase B: sum 16 partials, relu, cvt -> bf16 fk[2048][128]
//   grid.sync()
//   phase C: out tiles 64x32 via MFMA on relu'd bf16 fk

typedef __attribute__((ext_vector_type(8))) __bf16 bf16x8;
typedef __attribute__((ext_vector_type(4))) __bf16 bf16x4;
typedef __attribute__((ext_vector_type(4))) float floatx4;

#define KD     2048   // inner K of gemm1
#define NF     128    // feature count = K of gemm2
#define NA     1024   // rows of a (= rows of b = out dim)
#define NPART  16     // K-splits (K=128 each)
#define FKN    (2048 * 128)

static __device__ inline bf16x8 cvt8(float4 u, float4 v) {
    bf16x8 s;
    s[0] = (__bf16)u.x; s[1] = (__bf16)u.y; s[2] = (__bf16)u.z; s[3] = (__bf16)u.w;
    s[4] = (__bf16)v.x; s[5] = (__bf16)v.y; s[6] = (__bf16)v.z; s[7] = (__bf16)v.w;
    return s;
}

__global__ __launch_bounds__(256, 2) void fused(const float* __restrict__ A,
                                                const float* __restrict__ B,
                                                const float* __restrict__ F,
                                                float* __restrict__ part,
                                                __bf16* __restrict__ fkb,
                                                float* __restrict__ out) {
    // LDS union: phase A needs 64*40 + 128*40 = 7680 bf16 (15.4 KB)
    //            phase C needs 64*136 + 32*136 = 13056 bf16 (26.1 KB)
    __shared__ __bf16 smem[64 * 136 + 32 * 136];

    const int bid  = blockIdx.x;
    const int t    = threadIdx.x;
    const int lane = t & 63;
    const int w    = t >> 6;
    const int ln   = lane & 15;
    const int quad = lane >> 4;
    const int q8   = quad * 8;

    // ---------------- phase A: gemm1 split-K(16), partials ----------------
    {
        __bf16* Xs = smem;              // 64 rows x stride 40
        __bf16* Fs = smem + 64 * 40;    // 128 rows x stride 40

        const int bx = bid & 31;        // 32 row-tiles of 64
        const int s  = bid >> 5;        // 16 K-splits
        const int m0 = bx * 64;
        const int k0 = s * 128;
        const float* src = (m0 < NA) ? (A + (size_t)m0 * KD)
                                     : (B + (size_t)(m0 - NA) * KD);

        floatx4 acc[4][2];
#pragma unroll
        for (int mt = 0; mt < 4; mt++)
#pragma unroll
            for (int nt = 0; nt < 2; nt++)
                acc[mt][nt] = (floatx4){0.f, 0.f, 0.f, 0.f};

        const int xrow = t >> 2, xcol = (t & 3) * 8;    // 64 rows x 32 cols
        const int frow = t >> 1, fcol = (t & 1) * 16;   // 128 rows x 32 cols
        const float* xp = src + (size_t)xrow * KD + (k0 + xcol);
        const float* fp = F   + (size_t)frow * KD + (k0 + fcol);

        // register prefetch of kk=0
        float4 xu = *(const float4*)(xp + 0);
        float4 xv = *(const float4*)(xp + 4);
        float4 f0 = *(const float4*)(fp + 0);
        float4 f1 = *(const float4*)(fp + 4);
        float4 f2 = *(const float4*)(fp + 8);
        float4 f3 = *(const float4*)(fp + 12);

#pragma unroll
        for (int kk = 0; kk < 128; kk += 32) {
            *(bf16x8*)&Xs[xrow * 40 + xcol]     = cvt8(xu, xv);
            *(bf16x8*)&Fs[frow * 40 + fcol]     = cvt8(f0, f1);
            *(bf16x8*)&Fs[frow * 40 + fcol + 8] = cvt8(f2, f3);
            __syncthreads();

            if (kk + 32 < 128) {   // prefetch next kk while MFMAs run
                xu = *(const float4*)(xp + kk + 32);
                xv = *(const float4*)(xp + kk + 36);
                f0 = *(const float4*)(fp + kk + 32);
                f1 = *(const float4*)(fp + kk + 36);
                f2 = *(const float4*)(fp + kk + 40);
                f3 = *(const float4*)(fp + kk + 44);
            }

            bf16x8 bfrag[2];
#pragma unroll
            for (int nt = 0; nt < 2; nt++)
                bfrag[nt] = *(const bf16x8*)&Fs[(w * 32 + nt * 16 + ln) * 40 + q8];
#pragma unroll
            for (int mt = 0; mt < 4; mt++) {
                bf16x8 af = *(const bf16x8*)&Xs[(mt * 16 + ln) * 40 + q8];
#pragma unroll
                for (int nt = 0; nt < 2; nt++)
                    acc[mt][nt] = __builtin_amdgcn_mfma_f32_16x16x32_bf16(
                        af, bfrag[nt], acc[mt][nt], 0, 0, 0);
            }
            __syncthreads();
        }

        float* pdst = part + (size_t)s * FKN;
#pragma unroll
        for (int mt = 0; mt < 4; mt++)
#pragma unroll
            for (int nt = 0; nt < 2; nt++)
#pragma unroll
                for (int r = 0; r < 4; r++) {
                    int row = m0 + mt * 16 + quad * 4 + r;
                    int col = w * 32 + nt * 16 + ln;
                    pdst[(size_t)row * NF + col] = acc[mt][nt][r];
                }
    }

    cg::this_grid().sync();

    // ---------------- phase B: reduce + relu + cvt -> bf16 ----------------
    {
        int idx = bid * 256 + t;           // 131072 threads, 65536 float4 jobs
        if (idx < 65536) {
            size_t base = (size_t)idx * 4;
            float4 sum = make_float4(0.f, 0.f, 0.f, 0.f);
#pragma unroll
            for (int s = 0; s < NPART; s++) {
                float4 u = *(const float4*)(part + (size_t)s * FKN + base);
                sum.x += u.x; sum.y += u.y; sum.z += u.z; sum.w += u.w;
            }
            bf16x4 o;
            o[0] = (__bf16)fmaxf(sum.x, 0.f);
            o[1] = (__bf16)fmaxf(sum.y, 0.f);
            o[2] = (__bf16)fmaxf(sum.z, 0.f);
            o[3] = (__bf16)fmaxf(sum.w, 0.f);
            *(bf16x4*)(fkb + base) = o;
        }
    }

    cg::this_grid().sync();

    // ---------------- phase C: gemm2, 64x32 out tiles ----------------
    {
        __bf16* Ps = smem;               // 64 rows x stride 136
        __bf16* Qs = smem + 64 * 136;    // 32 rows x stride 136

        const int i0 = (bid >> 5) * 64;  // 16 i-tiles
        const int j0 = (bid & 31) * 32;  // 32 j-tiles

        {   // stage Ps: 64x128 (each thread 32 cols)
            const int prow = t >> 2, pcol = (t & 3) * 32;
            const __bf16* p = fkb + (size_t)(i0 + prow) * NF + pcol;
#pragma unroll
            for (int c = 0; c < 32; c += 8)
                *(bf16x8*)&Ps[prow * 136 + pcol + c] = *(const bf16x8*)(p + c);
        }
        {   // stage Qs: 32x128 (each thread 16 cols)
            const int qrow = t >> 3, qcol = (t & 7) * 16;
            const __bf16* q = fkb + (size_t)(NA + j0 + qrow) * NF + qcol;
#pragma unroll
            for (int c = 0; c < 16; c += 8)
                *(bf16x8*)&Qs[qrow * 136 + qcol + c] = *(const bf16x8*)(q + c);
        }
        __syncthreads();

        const int wm = w & 1;   // 2 row-halves of 32
        const int wn = w >> 1;  // 2 col-halves of 16

        floatx4 acc2[2];
        acc2[0] = (floatx4){0.f, 0.f, 0.f, 0.f};
        acc2[1] = (floatx4){0.f, 0.f, 0.f, 0.f};

#pragma unroll
        for (int k0 = 0; k0 < 128; k0 += 32) {
            bf16x8 bfq = *(const bf16x8*)&Qs[(wn * 16 + ln) * 136 + k0 + q8];
#pragma unroll
            for (int mt = 0; mt < 2; mt++) {
                bf16x8 af = *(const bf16x8*)&Ps[(wm * 32 + mt * 16 + ln) * 136 + k0 + q8];
                acc2[mt] = __builtin_amdgcn_mfma_f32_16x16x32_bf16(
                    af, bfq, acc2[mt], 0, 0, 0);
            }
        }

#pragma unroll
        for (int mt = 0; mt < 2; mt++)
#pragma unroll
            for (int r = 0; r < 4; r++) {
                int row = i0 + wm * 32 + mt * 16 + quad * 4 + r;
                int col = j0 + wn * 16 + ln;
                out[(size_t)row * 1024 + col] = acc2[mt][r];
            }
    }
}

extern "C" void kernel_launch(void* const* d_in, const int* in_sizes, int n_in,
                              void* d_out, int out_size, void* d_ws, size_t ws_size,
                              hipStream_t stream) {
    const float* a     = (const float*)d_in[0];
    const float* b     = (const float*)d_in[1];
    const float* feats = (const float*)d_in[2];
    float* out = (float*)d_out;

    float*   part = (float*)d_ws;                                      // 16 MB fp32 partials
    __bf16*  fkb  = (__bf16*)((char*)d_ws + (size_t)NPART * FKN * 4);  // 512 KB bf16

    void* args[] = { (void*)&a, (void*)&b, (void*)&feats,
                     (void*)&part, (void*)&fkb, (void*)&out };
    hipLaunchCooperativeKernel((const void*)fused, dim3(512), dim3(256),
                               args, 0, stream);
}

// Round 2
// 88.719 us; speedup vs baseline: 2.3578x; 2.3578x over previous
//
#include <hip/hip_runtime.h>

// out[1024][1024] = relu(a @ feats^T) @ relu(b @ feats^T)^T
//   a,b: [1024][2048] fp32, feats: [128][2048] fp32, out fp32.
// Pipeline (2 kernels + 1 tiny memset, no grid barrier, no partial round-trip):
//   memset fk (1 MB fp32)
//   gemm1_atomic: [a;b] @ feats^T split-K(16), blocks atomicAdd fp32 into fk[2048][128]
//   gemm2       : stage fk with relu+cvt->bf16 in regs, MFMA 64x32 out tiles

typedef __attribute__((ext_vector_type(8))) __bf16 bf16x8;
typedef __attribute__((ext_vector_type(4))) float floatx4;

#define KD     2048   // inner K of gemm1
#define NF     128    // feature count = K of gemm2
#define NA     1024   // rows of a (= rows of b = out dim)
#define NPART  16     // K-splits (K=128 each)

static __device__ inline bf16x8 cvt8(float4 u, float4 v) {
    bf16x8 s;
    s[0] = (__bf16)u.x; s[1] = (__bf16)u.y; s[2] = (__bf16)u.z; s[3] = (__bf16)u.w;
    s[4] = (__bf16)v.x; s[5] = (__bf16)v.y; s[6] = (__bf16)v.z; s[7] = (__bf16)v.w;
    return s;
}

// relu applied during fp32 -> bf16 conversion (gemm2 staging)
static __device__ inline bf16x8 cvt8r(float4 u, float4 v) {
    bf16x8 s;
    s[0] = (__bf16)fmaxf(u.x, 0.f); s[1] = (__bf16)fmaxf(u.y, 0.f);
    s[2] = (__bf16)fmaxf(u.z, 0.f); s[3] = (__bf16)fmaxf(u.w, 0.f);
    s[4] = (__bf16)fmaxf(v.x, 0.f); s[5] = (__bf16)fmaxf(v.y, 0.f);
    s[6] = (__bf16)fmaxf(v.z, 0.f); s[7] = (__bf16)fmaxf(v.w, 0.f);
    return s;
}

// ---- gemm1_atomic: fk[2048][128] += X[m, s*128:(s+1)*128] . feats[:, same]^T
// grid (32, 16): x = 64-row tile of [a;b], y = K-split. block = 4 waves;
// wave w covers n-cols [w*32, w*32+32). Output via fp32 atomics (16-way split sum).
__global__ __launch_bounds__(256) void gemm1_atomic(const float* __restrict__ A,
                                                    const float* __restrict__ B,
                                                    const float* __restrict__ F,
                                                    float* __restrict__ fk) {
    __shared__ __bf16 Xs[64 * 40];    // 32 cols used, stride 40
    __shared__ __bf16 Fs[128 * 40];

    const int t    = threadIdx.x;
    const int m0   = blockIdx.x * 64;
    const int s    = blockIdx.y;
    const int k0   = s * 128;
    const float* src = (m0 < NA) ? (A + (size_t)m0 * KD)
                                 : (B + (size_t)(m0 - NA) * KD);

    const int lane = t & 63;
    const int w    = t >> 6;
    const int ln   = lane & 15;
    const int quad = lane >> 4;
    const int q8   = quad * 8;

    floatx4 acc[4][2];
#pragma unroll
    for (int mt = 0; mt < 4; mt++)
#pragma unroll
        for (int nt = 0; nt < 2; nt++)
            acc[mt][nt] = (floatx4){0.f, 0.f, 0.f, 0.f};

    const int xrow = t >> 2, xcol = (t & 3) * 8;    // 64 rows x 32 cols
    const int frow = t >> 1, fcol = (t & 1) * 16;   // 128 rows x 32 cols
    const float* xp = src + (size_t)xrow * KD + (k0 + xcol);
    const float* fp = F   + (size_t)frow * KD + (k0 + fcol);

    // register prefetch of kk=0
    float4 xu = *(const float4*)(xp + 0);
    float4 xv = *(const float4*)(xp + 4);
    float4 f0 = *(const float4*)(fp + 0);
    float4 f1 = *(const float4*)(fp + 4);
    float4 f2 = *(const float4*)(fp + 8);
    float4 f3 = *(const float4*)(fp + 12);

#pragma unroll
    for (int kk = 0; kk < 128; kk += 32) {
        *(bf16x8*)&Xs[xrow * 40 + xcol]     = cvt8(xu, xv);
        *(bf16x8*)&Fs[frow * 40 + fcol]     = cvt8(f0, f1);
        *(bf16x8*)&Fs[frow * 40 + fcol + 8] = cvt8(f2, f3);
        __syncthreads();

        if (kk + 32 < 128) {   // prefetch next kk while MFMAs run
            xu = *(const float4*)(xp + kk + 32);
            xv = *(const float4*)(xp + kk + 36);
            f0 = *(const float4*)(fp + kk + 32);
            f1 = *(const float4*)(fp + kk + 36);
            f2 = *(const float4*)(fp + kk + 40);
            f3 = *(const float4*)(fp + kk + 44);
        }

        bf16x8 bfrag[2];
#pragma unroll
        for (int nt = 0; nt < 2; nt++)
            bfrag[nt] = *(const bf16x8*)&Fs[(w * 32 + nt * 16 + ln) * 40 + q8];
#pragma unroll
        for (int mt = 0; mt < 4; mt++) {
            bf16x8 af = *(const bf16x8*)&Xs[(mt * 16 + ln) * 40 + q8];
#pragma unroll
            for (int nt = 0; nt < 2; nt++)
                acc[mt][nt] = __builtin_amdgcn_mfma_f32_16x16x32_bf16(
                    af, bfrag[nt], acc[mt][nt], 0, 0, 0);
        }
        __syncthreads();
    }

    // accumulate this split's contribution directly into fk (fp32 atomics)
#pragma unroll
    for (int mt = 0; mt < 4; mt++)
#pragma unroll
        for (int nt = 0; nt < 2; nt++)
#pragma unroll
            for (int r = 0; r < 4; r++) {
                int row = m0 + mt * 16 + quad * 4 + r;
                int col = w * 32 + nt * 16 + ln;
                atomicAdd(&fk[(size_t)row * NF + col], acc[mt][nt][r]);
            }
}

// ---- gemm2: out[i][j] = sum_f relu(fk[i][f]) * relu(fk[1024+j][f]) ----
// grid (32,16): 64x32 out tiles; block = 4 waves (2x2); relu+cvt during staging.
__global__ __launch_bounds__(256) void gemm2(const float* __restrict__ fk,
                                             float* __restrict__ out) {
    __shared__ __bf16 Ps[64 * 136];
    __shared__ __bf16 Qs[32 * 136];

    const int t    = threadIdx.x;
    const int i0   = blockIdx.y * 64;
    const int j0   = blockIdx.x * 32;
    const int lane = t & 63;
    const int w    = t >> 6;
    const int ln   = lane & 15;
    const int quad = lane >> 4;
    const int q8   = quad * 8;

    {   // stage Ps: 64x128 fp32 -> relu -> bf16 (each thread 32 cols)
        const int prow = t >> 2, pcol = (t & 3) * 32;
        const float* p = fk + (size_t)(i0 + prow) * NF + pcol;
#pragma unroll
        for (int c = 0; c < 32; c += 8) {
            float4 u = *(const float4*)(p + c);
            float4 v = *(const float4*)(p + c + 4);
            *(bf16x8*)&Ps[prow * 136 + pcol + c] = cvt8r(u, v);
        }
    }
    {   // stage Qs: 32x128 fp32 -> relu -> bf16 (each thread 16 cols)
        const int qrow = t >> 3, qcol = (t & 7) * 16;
        const float* q = fk + (size_t)(NA + j0 + qrow) * NF + qcol;
#pragma unroll
        for (int c = 0; c < 16; c += 8) {
            float4 u = *(const float4*)(q + c);
            float4 v = *(const float4*)(q + c + 4);
            *(bf16x8*)&Qs[qrow * 136 + qcol + c] = cvt8r(u, v);
        }
    }
    __syncthreads();

    const int wm = w & 1;   // 2 row-halves of 32
    const int wn = w >> 1;  // 2 col-halves of 16

    floatx4 acc2[2];
    acc2[0] = (floatx4){0.f, 0.f, 0.f, 0.f};
    acc2[1] = (floatx4){0.f, 0.f, 0.f, 0.f};

#pragma unroll
    for (int k0 = 0; k0 < 128; k0 += 32) {
        bf16x8 bfq = *(const bf16x8*)&Qs[(wn * 16 + ln) * 136 + k0 + q8];
#pragma unroll
        for (int mt = 0; mt < 2; mt++) {
            bf16x8 af = *(const bf16x8*)&Ps[(wm * 32 + mt * 16 + ln) * 136 + k0 + q8];
            acc2[mt] = __builtin_amdgcn_mfma_f32_16x16x32_bf16(
                af, bfq, acc2[mt], 0, 0, 0);
        }
    }

#pragma unroll
    for (int mt = 0; mt < 2; mt++)
#pragma unroll
        for (int r = 0; r < 4; r++) {
            int row = i0 + wm * 32 + mt * 16 + quad * 4 + r;
            int col = j0 + wn * 16 + ln;
            out[(size_t)row * 1024 + col] = acc2[mt][r];
        }
}

extern "C" void kernel_launch(void* const* d_in, const int* in_sizes, int n_in,
                              void* d_out, int out_size, void* d_ws, size_t ws_size,
                              hipStream_t stream) {
    const float* a     = (const float*)d_in[0];
    const float* b     = (const float*)d_in[1];
    const float* feats = (const float*)d_in[2];
    float* out = (float*)d_out;

    float* fk = (float*)d_ws;   // 2048 x 128 fp32 accumulator (1 MB)

    hipMemsetAsync(fk, 0, (size_t)2048 * NF * sizeof(float), stream);
    gemm1_atomic<<<dim3(32, NPART), 256, 0, stream>>>(a, b, feats, fk);
    gemm2<<<dim3(32, 16), 256, 0, stream>>>(fk, out);
}